// Round 3
// baseline (741.475 us; speedup 1.0000x reference)
//
#include <hip/hip_runtime.h>

// GsumLayer: out[b] = a[b] @ x[b], B=8, N=4096, D=32, fp32 in/out.
//
// v3 theory: prior kernels streamed `a` as ~32K concurrent row-streams at
// 64-128B per touch -> DRAM page thrash -> ~0.75 TB/s. This version reads
// `a` in 1-KB-contiguous bursts (one wave instruction = 1 KB of ONE row),
// 16 KB per wave-chunk in flight, so each DRAM page activation serves >=16
// lines. Split-bf16 MFMA (hi*hi + lo*hi + hi*lo) keeps compute off the
// critical path; x is pre-split/transposed to bf16 xT_hi/lo [B][32][4096]
// in d_ws (4 MB, L2-resident) so B-fragments are direct L2 dwordx4 loads.
// All work is wave-private: per-wave LDS slice, ZERO barriers, frag+stage
// prefetch one full chunk ahead, frag-issue pinned before stage-issue so
// in-order vmcnt never drains the HBM stream for an L2 hit.
//
// Input order per setup_inputs(): d_in[0] = x [B,N,D], d_in[1] = a [B,N,N].

#define GN 4096
#define GD 32
#define GB 8
#define BKC 256           // k per chunk (1 KB per row per chunk)
#define NCH (GN / BKC)    // 16 chunks
#define NT 512            // 8 waves
#define NW 8
#define TILE_N 128        // 8 waves x 16 rows

typedef float f32x4 __attribute__((ext_vector_type(4)));
typedef short s16x8 __attribute__((ext_vector_type(8)));

// ---------------- pre-kernel: x [B,N,D] fp32 -> xT_hi/xT_lo [B,D,N] bf16 ---
__global__ __launch_bounds__(256, 4) void xprep(
    const float* __restrict__ x,
    unsigned short* __restrict__ xth,
    unsigned short* __restrict__ xtl)
{
    const int t  = threadIdx.x;
    const int b  = blockIdx.x >> 5;   // 0..7
    const int kc = blockIdx.x & 31;   // 32 chunks of 128 k
    const int d  = t & 31;
    const int kb = t >> 5;            // 0..7
    const int k0 = kc * 128 + kb * 16;
    const float* xb = x + (long long)b * GN * GD;

    __attribute__((aligned(16))) unsigned short hi[16];
    __attribute__((aligned(16))) unsigned short lo[16];
    #pragma unroll
    for (int j = 0; j < 16; ++j) {
        float f = xb[(long long)(k0 + j) * GD + d];   // lanes d=0..31 coalesced
        unsigned u  = __float_as_uint(f);
        unsigned hb = (u + 0x8000u) >> 16;
        float hif   = __uint_as_float(hb << 16);
        hi[j] = (unsigned short)hb;
        lo[j] = (unsigned short)((__float_as_uint(f - hif) + 0x8000u) >> 16);
    }
    long long ob = ((long long)(b * GD + d)) * GN + k0;
    *(s16x8*)(xth + ob)     = *(const s16x8*)&hi[0];
    *(s16x8*)(xth + ob + 8) = *(const s16x8*)&hi[8];
    *(s16x8*)(xtl + ob)     = *(const s16x8*)&lo[0];
    *(s16x8*)(xtl + ob + 8) = *(const s16x8*)&lo[8];
}

// ---------------- main kernel ---------------------------------------------
__global__ __launch_bounds__(NT, 2) void gsum_mfma(
    const float* __restrict__ a,
    const unsigned short* __restrict__ xth,  // [GB][GD][GN] bf16 hi
    const unsigned short* __restrict__ xtl,  // [GB][GD][GN] bf16 lo
    float* __restrict__ out)
{
    __shared__ float As[NW][16][BKC];        // 8 x 16 KB = 128 KB, wave-private

    const int t  = threadIdx.x;
    const int w  = t >> 6;        // wave 0..7
    const int l  = t & 63;
    const int m  = l & 15;        // MFMA row/col index
    const int kg = l >> 4;        // MFMA k-group 0..3
    const int m7 = m & 7;

    const int b    = blockIdx.x >> 5;
    const int tile = blockIdx.x & 31;
    const int n0   = tile * TILE_N + w * 16;

    const float* Ab = a + ((long long)b * GN + n0) * GN;     // wave's 16 rows
    const unsigned short* xh0p = xth + (long long)(b * GD + m) * GN;       // d=m
    const unsigned short* xh1p = xh0p + 16 * GN;                           // d=m+16
    const unsigned short* xl0p = xtl + (long long)(b * GD + m) * GN;
    const unsigned short* xl1p = xl0p + 16 * GN;
    const int kfo = kg * 8;

    float* lds = &As[w][0][0];    // wave slice

    f32x4 acc0 = {0.f, 0.f, 0.f, 0.f};
    f32x4 acc1 = {0.f, 0.f, 0.f, 0.f};
    s16x8 xf[8][4];               // x fragments for one chunk (static-indexed)
    f32x4 st[16];                 // staged a chunk (1 KB x 16 rows)

    // stage chunk c: one dwordx4 instruction per row = 1 KB contiguous burst
    auto STAGE = [&](int c) {
        const float* p = Ab + c * BKC + l * 4;
        #pragma unroll
        for (int r = 0; r < 16; ++r)
            st[r] = *(const f32x4*)(p + (long long)r * GN);
    };
    // write staged chunk to wave LDS slice, XOR-granule swizzle (write side)
    auto DSWRITE = [&]() {
        #pragma unroll
        for (int r = 0; r < 16; ++r)
            *(f32x4*)(lds + r * BKC + ((l ^ (r & 7)) * 4)) = st[r];
    };
    // x fragments for chunk c (L2-resident xT, 16 B contiguous each)
    auto FRAGS = [&](int c) {
        #pragma unroll
        for (int s = 0; s < 8; ++s) {
            const long long k = (long long)c * BKC + s * 32 + kfo;
            xf[s][0] = *(const s16x8*)(xh0p + k);
            xf[s][1] = *(const s16x8*)(xh1p + k);
            xf[s][2] = *(const s16x8*)(xl0p + k);
            xf[s][3] = *(const s16x8*)(xl1p + k);
        }
    };
    // consume chunk in LDS + xf: 8 K-steps, 6 MFMAs each (3-term split, 2 d-halves)
    auto COMPUTE = [&]() {
        #pragma unroll
        for (int s = 0; s < 8; ++s) {
            const int g0 = (((s * 8 + kg * 2)     ^ m7) * 4);
            const int g1 = (((s * 8 + kg * 2 + 1) ^ m7) * 4);
            f32x4 fa = *(const f32x4*)(lds + m * BKC + g0);
            f32x4 fb = *(const f32x4*)(lds + m * BKC + g1);
            s16x8 ahi, alo;
            #pragma unroll
            for (int e = 0; e < 4; ++e) {
                {
                    unsigned u  = __float_as_uint(fa[e]);
                    unsigned hb = (u + 0x8000u) >> 16;
                    ahi[e] = (short)hb;
                    float hif = __uint_as_float(hb << 16);
                    alo[e] = (short)((__float_as_uint(fa[e] - hif) + 0x8000u) >> 16);
                }
                {
                    unsigned u  = __float_as_uint(fb[e]);
                    unsigned hb = (u + 0x8000u) >> 16;
                    ahi[4 + e] = (short)hb;
                    float hif = __uint_as_float(hb << 16);
                    alo[4 + e] = (short)((__float_as_uint(fb[e] - hif) + 0x8000u) >> 16);
                }
            }
            acc0 = __builtin_amdgcn_mfma_f32_16x16x32_bf16(ahi, xf[s][0], acc0, 0, 0, 0);
            acc1 = __builtin_amdgcn_mfma_f32_16x16x32_bf16(ahi, xf[s][1], acc1, 0, 0, 0);
            acc0 = __builtin_amdgcn_mfma_f32_16x16x32_bf16(alo, xf[s][0], acc0, 0, 0, 0);
            acc1 = __builtin_amdgcn_mfma_f32_16x16x32_bf16(alo, xf[s][1], acc1, 0, 0, 0);
            acc0 = __builtin_amdgcn_mfma_f32_16x16x32_bf16(ahi, xf[s][2], acc0, 0, 0, 0);
            acc1 = __builtin_amdgcn_mfma_f32_16x16x32_bf16(ahi, xf[s][3], acc1, 0, 0, 0);
        }
    };

    // ---- prologue: LDS <- chunk 0; prefetch frags(0) then stage(1) ----
    STAGE(0);
    DSWRITE();                               // auto vmcnt on st deps
    FRAGS(0);
    __builtin_amdgcn_sched_barrier(0);       // pin: frags issue before staging
    STAGE(1);
    __builtin_amdgcn_sched_barrier(0);

    // ---- main loop: zero barriers, wave-private pipeline ----
    for (int c = 0; c < NCH; ++c) {
        COMPUTE();                           // chunk c (LDS + xf)
        __builtin_amdgcn_sched_barrier(0);
        if (c + 1 < NCH) {
            DSWRITE();                       // chunk c+1 -> LDS (in-order ds ops)
            __builtin_amdgcn_sched_barrier(0);
            FRAGS(c + 1);                    // issue L2 frags first...
            __builtin_amdgcn_sched_barrier(0);
            if (c + 2 < NCH) {
                STAGE(c + 2);                // ...then the HBM burst stream
                __builtin_amdgcn_sched_barrier(0);
            }
        }
    }

    // ---- epilogue: D col = lane&15 (d), row = kg*4+j (a-row) ----
    float* Ob = out + ((long long)b * GN + n0) * GD;
    #pragma unroll
    for (int j = 0; j < 4; ++j) {
        Ob[(kg * 4 + j) * GD + m]      = acc0[j];
        Ob[(kg * 4 + j) * GD + 16 + m] = acc1[j];
    }
}

extern "C" void kernel_launch(void* const* d_in, const int* in_sizes, int n_in,
                              void* d_out, int out_size, void* d_ws, size_t ws_size,
                              hipStream_t stream) {
    const float* x = (const float*)d_in[0];  // [B, N, D]
    const float* a = (const float*)d_in[1];  // [B, N, N]
    float* out = (float*)d_out;              // [B, N, D]

    // workspace: xT_hi (2 MB) + xT_lo (2 MB), bf16 [B][32][4096]
    unsigned short* xth = (unsigned short*)d_ws;
    unsigned short* xtl = xth + (long long)GB * GD * GN;

    xprep<<<dim3(GB * 32), dim3(256), 0, stream>>>(x, xth, xtl);
    gsum_mfma<<<dim3(GB * (GN / TILE_N)), dim3(NT), 0, stream>>>(a, xth, xtl, out);
}